// Round 1
// baseline (549.473 us; speedup 1.0000x reference)
//
#include <hip/hip_runtime.h>
#include <hip/hip_bf16.h>

// Problem constants
#define BB 4
#define SS 4096
#define DM 1024
#define HH 16
#define PP 32
#define RR 8
#define DD 64
#define NTOK (BB*SS)          // 16384 tokens
#define MM NTOK               // GEMM M
#define NN DM                 // GEMM N
#define KK DM                 // GEMM K

typedef __attribute__((ext_vector_type(8))) short short8;
typedef __attribute__((ext_vector_type(4))) float floatx4;

// ---------------------------------------------------------------------------
// Kernel 1: convert W_out (f32 [k][n] row-major) -> bf16, pre-swizzled into
// MFMA B-fragment order. Fragment block id = (ntile in [0,64), kblk in [0,32)),
// stored at element offset ((ntile*32 + kblk)*512) + lane*8 + j, holding
// B[k = kblk*32 + (lane>>4)*8 + j][n = ntile*16 + (lane&15)].
// ---------------------------------------------------------------------------
__global__ __launch_bounds__(256) void convert_w(const float* __restrict__ Wo,
                                                 __hip_bfloat16* __restrict__ wsw) {
    int tid = blockIdx.x * 256 + threadIdx.x;     // 0 .. 131071
    int l = tid & 63;
    int kblk = (tid >> 6) & 31;
    int ntile = tid >> 11;
    int col = ntile * 16 + (l & 15);
    int krow = kblk * 32 + (l >> 4) * 8;
#pragma unroll
    for (int j = 0; j < 8; ++j) {
        wsw[(size_t)tid * 8 + j] = __float2bfloat16(Wo[(size_t)(krow + j) * NN + col]);
    }
}

// ---------------------------------------------------------------------------
// Kernel 2: router + sparse SSE attention. One wave per (token, head).
// Block = 256 threads = 4 independent waves. Head-major block order for L2
// locality on W_router/K_state/V_state.
// Writes heads as bf16 into hb[token*DM + h*DD + d] (the GEMM A matrix).
// ---------------------------------------------------------------------------
__global__ __launch_bounds__(256) void attn_kernel(const float* __restrict__ x,
                                                   const float* __restrict__ Kst,
                                                   const float* __restrict__ Vst,
                                                   const float* __restrict__ Wr,
                                                   const int* __restrict__ kp,
                                                   __hip_bfloat16* __restrict__ hb) {
    __shared__ float xs[4][64];
    const int lane = threadIdx.x & 63;
    const int wave = threadIdx.x >> 6;
    const int bid  = blockIdx.x * 4 + wave;       // 0 .. 262143
    const int t = bid & (NTOK - 1);               // token (fast)
    const int h = bid >> 14;                      // head  (slow)

    // Stage token-head slice of x into LDS (one float per lane)
    float xv = x[(size_t)t * DM + h * DD + lane];
    xs[wave][lane] = xv;
    __syncthreads();

    const int kk = kp[0];

    // ---- logits (fp32): lane l computes partial for p = l&31 over half of d
    const int p  = lane & 31;
    const int dh = lane >> 5;
    const float* wrow = Wr + (size_t)h * (DD * PP) + dh * 32 * PP + p;
    float lg = 0.f;
#pragma unroll
    for (int dd = 0; dd < 32; ++dd)
        lg += xs[wave][dh * 32 + dd] * wrow[dd * PP];
    lg += __shfl_xor(lg, 32);                     // both halves hold full logit_p

    // ---- top-k threshold: k iterations of argmax-with-exclusion
    float thresh = 0.f, m1 = 0.f;
    {
        int active = 1;
        for (int it = 0; it < kk; ++it) {
            float v = active ? lg : -INFINITY;
            int vi = p;
#pragma unroll
            for (int off = 1; off < 64; off <<= 1) {
                float ov = __shfl_xor(v, off);
                int   oi = __shfl_xor(vi, off);
                if (ov > v || (ov == v && oi < vi)) { v = ov; vi = oi; }
            }
            if (it == 0) m1 = v;
            thresh = v;
            if (vi == p) active = 0;
        }
    }

    // ---- gates: softmax over selected logits (>= thresh, matching ref)
    const bool selme = (lg >= thresh);
    float ex = selme ? expf(lg - m1) : 0.f;
    float es = ex;
    es += __shfl_xor(es, 1);  es += __shfl_xor(es, 2);  es += __shfl_xor(es, 4);
    es += __shfl_xor(es, 8);  es += __shfl_xor(es, 16);
    const float gate = ex / es;

    unsigned long long bal = __ballot(selme);
    unsigned sel = (unsigned)(bal & 0xffffffffull); // low 32 bits (halves duplicate)

    // ---- per-selected-expert scores -> softmax over R -> heads accumulation
    float hacc = 0.f;
    const int r  = lane >> 3;
    const int ds = lane & 7;
    while (sel) {
        const int ps = __ffs(sel) - 1;
        sel &= sel - 1;
        const float g = __shfl(gate, ps);
        const float* Kp = Kst + ((size_t)(h * PP + ps) * RR) * DD;
        float s = 0.f;
#pragma unroll
        for (int j = 0; j < 8; ++j)
            s += xs[wave][ds + 8 * j] * Kp[r * DD + ds + 8 * j];
        s += __shfl_xor(s, 1); s += __shfl_xor(s, 2); s += __shfl_xor(s, 4);
        float sc = s * 0.125f;                      // 1/sqrt(D)
        float mx = sc;
        mx = fmaxf(mx, __shfl_xor(mx, 8));
        mx = fmaxf(mx, __shfl_xor(mx, 16));
        mx = fmaxf(mx, __shfl_xor(mx, 32));
        float e = expf(sc - mx);
        float se = e;
        se += __shfl_xor(se, 8); se += __shfl_xor(se, 16); se += __shfl_xor(se, 32);
        const float w = (e / se) * g;               // lane holds w for its r
        const float* Vp = Vst + ((size_t)(h * PP + ps) * RR) * DD;
#pragma unroll
        for (int r2 = 0; r2 < 8; ++r2) {
            float wr = __shfl(w, r2 * 8);
            hacc += wr * Vp[r2 * DD + lane];
        }
    }

    hb[(size_t)t * DM + h * DD + lane] = __float2bfloat16(hacc);
}

// ---------------------------------------------------------------------------
// Kernel 3: out = heads(bf16) @ W_out(bf16, swizzled) + b_out, fp32 out.
// 128x128 block tile, 4 waves in 2x2, each wave 64x64 via 4x4 mfma 16x16x32.
// Fragments loaded directly from global (W is L2-resident; A rows are 16x64B
// segments). C/D layout: row=(lane>>4)*4+i, col=lane&15 (HW-verified).
// ---------------------------------------------------------------------------
__global__ __launch_bounds__(256) void gemm_kernel(const __hip_bfloat16* __restrict__ Abf,
                                                   const __hip_bfloat16* __restrict__ Bsw,
                                                   const float* __restrict__ bias,
                                                   float* __restrict__ C) {
    const int lane = threadIdx.x & 63;
    const int wave = threadIdx.x >> 6;
    const int wm = wave >> 1, wn = wave & 1;
    const int bm0 = blockIdx.y * 128;
    const int bn0 = blockIdx.x * 128;
    const int l15 = lane & 15, l4 = lane >> 4;

    const short* Ap = (const short*)Abf;
    const short* Bp = (const short*)Bsw;

    int aoff[4], boff[4];
#pragma unroll
    for (int mt = 0; mt < 4; ++mt)
        aoff[mt] = (bm0 + wm * 64 + mt * 16 + l15) * KK + l4 * 8;
#pragma unroll
    for (int nt = 0; nt < 4; ++nt)
        boff[nt] = (((bn0 >> 4) + wn * 4 + nt) * 32) * 512 + lane * 8;

    floatx4 acc[4][4] = {};

    for (int kb = 0; kb < 32; ++kb) {
        short8 a[4], b[4];
#pragma unroll
        for (int mt = 0; mt < 4; ++mt)
            a[mt] = *(const short8*)(Ap + aoff[mt] + kb * 32);
#pragma unroll
        for (int nt = 0; nt < 4; ++nt)
            b[nt] = *(const short8*)(Bp + boff[nt] + kb * 512);
#pragma unroll
        for (int mt = 0; mt < 4; ++mt)
#pragma unroll
            for (int nt = 0; nt < 4; ++nt)
                acc[mt][nt] = __builtin_amdgcn_mfma_f32_16x16x32_bf16(a[mt], b[nt], acc[mt][nt], 0, 0, 0);
    }

    // epilogue: add bias, store fp32
#pragma unroll
    for (int nt = 0; nt < 4; ++nt) {
        const int col = bn0 + wn * 64 + nt * 16 + l15;
        const float bv = bias[col];
#pragma unroll
        for (int mt = 0; mt < 4; ++mt) {
            const int row0 = bm0 + wm * 64 + mt * 16 + l4 * 4;
#pragma unroll
            for (int i = 0; i < 4; ++i)
                C[(size_t)(row0 + i) * NN + col] = acc[mt][nt][i] + bv;
        }
    }
}

// ---------------------------------------------------------------------------
extern "C" void kernel_launch(void* const* d_in, const int* in_sizes, int n_in,
                              void* d_out, int out_size, void* d_ws, size_t ws_size,
                              hipStream_t stream) {
    const float* x   = (const float*)d_in[0];
    const float* Kst = (const float*)d_in[1];
    const float* Vst = (const float*)d_in[2];
    const float* Wr  = (const float*)d_in[3];
    const float* Wo  = (const float*)d_in[4];
    const float* bo  = (const float*)d_in[5];
    const int*   kp  = (const int*)d_in[6];
    float* out = (float*)d_out;

    __hip_bfloat16* hb  = (__hip_bfloat16*)d_ws;                 // 16384x1024 bf16 = 32 MiB
    __hip_bfloat16* wsw = hb + (size_t)MM * KK;                  // 1024x1024 bf16 = 2 MiB

    convert_w<<<dim3(512), 256, 0, stream>>>(Wo, wsw);
    attn_kernel<<<dim3(NTOK * HH / 4), 256, 0, stream>>>(x, Kst, Vst, Wr, kp, hb);
    gemm_kernel<<<dim3(NN / 128, MM / 128), 256, 0, stream>>>(hb, wsw, bo, out);
}